// Round 7
// baseline (99.289 us; speedup 1.0000x reference)
//
#include <hip/hip_runtime.h>

#define NUM_SEG 256
#define WAY 2
#define NCH 128
#define HW 65536                     // 256*256
#define N_IMG 8
#define PIX_PER_BLK 2048
#define CHUNKS_PER_IMG 32
#define NTHREADS 1024
#define TOTAL_SEG (N_IMG * NUM_SEG)  // 2048
#define NBLOCKS (N_IMG * CHUNKS_PER_IMG)   // 256
#define PART_ELEMS (NUM_SEG * NCH)   // 32768
#define KW 64                        // pixels per K-window
#define NITER (PIX_PER_BLK / KW)     // 32
#define LDR 72                       // padded row, shorts (144 B, 16B-aligned)

typedef __attribute__((ext_vector_type(8))) short short8;
typedef __attribute__((ext_vector_type(4))) float f32x4;

static __device__ __forceinline__ unsigned short f2bf(float f) {
    unsigned int u = __float_as_uint(f);
    unsigned int r = u + 0x7FFFu + ((u >> 16) & 1u);
    return (unsigned short)(r >> 16);
}

static __device__ __forceinline__ short8 cvt8(float4 lo, float4 hi) {
    short8 r;
    r[0] = (short)f2bf(lo.x); r[1] = (short)f2bf(lo.y);
    r[2] = (short)f2bf(lo.z); r[3] = (short)f2bf(lo.w);
    r[4] = (short)f2bf(hi.x); r[5] = (short)f2bf(hi.y);
    r[6] = (short)f2bf(hi.z); r[7] = (short)f2bf(hi.w);
    return r;
}

// One-hot MFMA segment-sum; B-fragments built in VALU from segb (no OH tile).
// C[ch][seg] += F[ch][k] * (seg(k)==seg)
__global__ __launch_bounds__(NTHREADS, 4)
void seg_mfma_kernel(const float* __restrict__ img,
                     const int* __restrict__ mask,
                     const int* __restrict__ segs,
                     float* __restrict__ ws_part,      // [NBLOCKS][PART_ELEMS]
                     int* __restrict__ labcnt_g) {     // [TOTAL_SEG][WAY]
    __shared__ __align__(16) unsigned short At[2][NCH][LDR];   // 36.9 KB bf16 A
    __shared__ __align__(8) unsigned char segb[PIX_PER_BLK];   // 2 KB
    __shared__ int labc[NUM_SEG * WAY];                        // 2 KB

    const int bid   = blockIdx.x;        // n*32 + chunk
    const int n     = bid >> 5;
    const int chunk = bid & 31;
    const int t     = threadIdx.x;
    const int lane  = t & 63;
    const int w     = t >> 6;            // wave 0..15
    const int mg    = w & 3;             // ch group base 32*mg
    const int ng    = w >> 2;            // seg group base 64*ng

    const long pixbase = (long)n * HW + chunk * PIX_PER_BLK;

    for (int i = t; i < NUM_SEG * WAY; i += NTHREADS) labc[i] = 0;
    __syncthreads();

    // stage seg ids (u8) + label histogram
    for (int p = t; p < PIX_PER_BLK; p += NTHREADS) {
        int s = segs[pixbase + p];
        segb[p] = (unsigned char)s;
        atomicAdd(&labc[s * 2 + mask[pixbase + p]], 1);
    }

    // A staging: 8 threads/row, 8 consecutive floats each -> 256 B/row contiguous
    const int arow = t >> 3;             // 0..127
    const int acol = (t & 7) * 8;        // 0..56
    const float* gA = img + (long)(n * NCH + arow) * HW
                          + chunk * PIX_PER_BLK + acol;

    // prologue: window 0 into At[0], window 1 loads in regs
    float4 fa = *(const float4*)(gA);
    float4 fb = *(const float4*)(gA + 4);
    __syncthreads();                      // segb visible
    *(short8*)&At[0][arow][acol] = cvt8(fa, fb);
    fa = *(const float4*)(gA + KW);
    fb = *(const float4*)(gA + KW + 4);
    __syncthreads();                      // At[0] visible

    f32x4 acc[2][4] = {};
    const int l15 = lane & 15;
    const int kA  = 8 * (lane >> 4);
    const unsigned short one = 0x3F80;    // bf16 1.0

    for (int it = 0; it < NITER; ++it) {
        const int cur = it & 1;

        // issue loads for window it+2 (consumed next iteration)
        float4 na = fa, nb = fb;
        if (it + 2 < NITER) {
            const float* g = gA + (it + 2) * KW;
            na = *(const float4*)(g);
            nb = *(const float4*)(g + 4);
        }

        // MFMA over At[cur]: 2 k-chunks
        #pragma unroll
        for (int kc = 0; kc < 2; ++kc) {
            const int kb = kc * 32 + kA;
            short8 a0 = *(const short8*)&At[cur][32 * mg      + l15][kb];
            short8 a1 = *(const short8*)&At[cur][32 * mg + 16 + l15][kb];
            // 8 segb bytes for this lane's k-slice (16 lanes share -> broadcast)
            uint2 sw = *(const uint2*)&segb[it * KW + kb];
            int sb[8];
            sb[0] = (sw.x      ) & 255; sb[1] = (sw.x >>  8) & 255;
            sb[2] = (sw.x >> 16) & 255; sb[3] = (sw.x >> 24) & 255;
            sb[4] = (sw.y      ) & 255; sb[5] = (sw.y >>  8) & 255;
            sb[6] = (sw.y >> 16) & 255; sb[7] = (sw.y >> 24) & 255;
            #pragma unroll
            for (int nj = 0; nj < 4; ++nj) {
                const int tgt = 64 * ng + 16 * nj + l15;
                short8 b;
                #pragma unroll
                for (int j = 0; j < 8; ++j)
                    b[j] = (sb[j] == tgt) ? (short)one : (short)0;
                acc[0][nj] = __builtin_amdgcn_mfma_f32_16x16x32_bf16(a0, b, acc[0][nj], 0, 0, 0);
                acc[1][nj] = __builtin_amdgcn_mfma_f32_16x16x32_bf16(a1, b, acc[1][nj], 0, 0, 0);
            }
        }

        // stage window it+1 into the other buffer (disjoint from cur)
        if (it + 1 < NITER)
            *(short8*)&At[cur ^ 1][arow][acol] = cvt8(fa, fb);
        __syncthreads();
        fa = na; fb = nb;
    }

    // epilogue: 4 concurrent 8 KB strips (reuse At, 36.9 KB), 4 rounds
    float (*strips)[16 * NCH] = (float (*)[16 * NCH])&At[0][0][0];
    float* wsb = ws_part + (long)bid * PART_ELEMS;
    #pragma unroll
    for (int nj = 0; nj < 4; ++nj) {
        // D layout: col(seg-local)=lane&15, row(ch-local)=4*(lane>>4)+r
        #pragma unroll
        for (int m = 0; m < 2; ++m)
            #pragma unroll
            for (int r = 0; r < 4; ++r)
                strips[ng][l15 * NCH + 32 * mg + 16 * m + 4 * (lane >> 4) + r] =
                    acc[m][nj][r];
        __syncthreads();
        {   // copy all 4 strips: thread t -> strip t>>8, 8 floats at (t&255)*8
            const int sidx = t >> 8;
            const int off  = (t & 255) * 8;
            const float4* src = (const float4*)&strips[sidx][off];
            float4 v0 = src[0], v1 = src[1];
            float* dst = wsb + (64 * sidx + 16 * nj) * NCH + off;
            ((float4*)dst)[0] = v0;
            ((float4*)dst)[1] = v1;
        }
        __syncthreads();
    }

    for (int i = t; i < NUM_SEG * WAY; i += NTHREADS)
        atomicAdd(&labcnt_g[n * NUM_SEG * WAY + i], labc[i]);
}

// sum 32 chunk-partials, divide by count, emit labels
__global__ void reduce_ws_kernel(const float* __restrict__ ws_part,
                                 const int* __restrict__ labcnt,
                                 float* __restrict__ out) {
    const int nmean = TOTAL_SEG * NCH;    // 262144
    int i = blockIdx.x * blockDim.x + threadIdx.x;
    if (i < nmean) {
        int nimg = i >> 15;               // / 32768
        int rem  = i & 32767;             // s*128 + c
        const float* base = ws_part + (long)nimg * 32 * PART_ELEMS + rem;
        float acc = 0.0f;
        #pragma unroll
        for (int j = 0; j < CHUNKS_PER_IMG; ++j)
            acc += base[(long)j * PART_ELEMS];
        int g  = i >> 7;                  // n*256 + s
        int c0 = labcnt[g * 2 + 0];
        int c1 = labcnt[g * 2 + 1];
        out[i] = acc / fmaxf((float)(c0 + c1), 1.0f);
    } else if (i < nmean + TOTAL_SEG) {
        int g = i - nmean;
        out[i] = (labcnt[g * 2 + 1] > labcnt[g * 2 + 0]) ? 1.0f : 0.0f;
    }
}

extern "C" void kernel_launch(void* const* d_in, const int* in_sizes, int n_in,
                              void* d_out, int out_size, void* d_ws, size_t ws_size,
                              hipStream_t stream) {
    const float* img  = (const float*)d_in[0];   // (8,128,256,256) f32
    const int*   mask = (const int*)d_in[1];     // (8,256,256) i32 in [0,2)
    const int*   segs = (const int*)d_in[2];     // (8,256,256) i32 in [0,256)

    float* out = (float*)d_out;

    const size_t part_bytes = (size_t)NBLOCKS * PART_ELEMS * sizeof(float); // 32 MB
    float* ws_part = (float*)d_ws;
    int*   labcnt  = (int*)((char*)d_ws + part_bytes);

    hipMemsetAsync(labcnt, 0, (size_t)TOTAL_SEG * WAY * sizeof(int), stream);

    seg_mfma_kernel<<<NBLOCKS, NTHREADS, 0, stream>>>(
        img, mask, segs, ws_part, labcnt);

    const int totalThreads = TOTAL_SEG * NCH + TOTAL_SEG;   // 264192
    reduce_ws_kernel<<<(totalThreads + 255) / 256, 256, 0, stream>>>(
        ws_part, labcnt, out);
}

// Round 8
// 83.833 us; speedup vs baseline: 1.1844x; 1.1844x over previous
//
#include <hip/hip_runtime.h>

#define NUM_SEG 256
#define WAY 2
#define NCH 128
#define CHB 64                       // channels per block (ch-split)
#define HW 65536                     // 256*256
#define N_IMG 8
#define PIX_PER_BLK 2048
#define CHUNKS_PER_IMG 32
#define NTHREADS 1024
#define TOTAL_SEG (N_IMG * NUM_SEG)  // 2048
#define NPART (N_IMG * CHUNKS_PER_IMG)     // 256 partial tiles (ws layout unchanged)
#define NBLOCKS (NPART * 2)          // 512 blocks, 2 per CU
#define PART_ELEMS (NUM_SEG * NCH)   // 32768
#define KW 32                        // pixels per K-chunk
#define NITER (PIX_PER_BLK / KW)     // 64
#define LDR 40                       // padded row, shorts (80 B, 16B-aligned)

typedef __attribute__((ext_vector_type(8))) short short8;
typedef __attribute__((ext_vector_type(2))) short short2v;
typedef __attribute__((ext_vector_type(4))) float f32x4;

static __device__ __forceinline__ unsigned short f2bf(float f) {
    unsigned int u = __float_as_uint(f);
    unsigned int r = u + 0x7FFFu + ((u >> 16) & 1u);
    return (unsigned short)(r >> 16);
}

static __device__ __forceinline__ short2v cvt2(float2 v) {
    short2v r;
    r[0] = (short)f2bf(v.x); r[1] = (short)f2bf(v.y);
    return r;
}

// One-hot MFMA segment-sum, round-5 control flow, channel-split for 2 blocks/CU.
// Block (n, chunk, h) computes C[ch in h*64..][seg] over 2048 px.
__global__ __launch_bounds__(NTHREADS, 8)
void seg_mfma_kernel(const float* __restrict__ img,
                     const int* __restrict__ mask,
                     const int* __restrict__ segs,
                     float* __restrict__ ws_part,      // [NPART][256 seg][128 ch]
                     int* __restrict__ labcnt_g) {     // [TOTAL_SEG][WAY]
    __shared__ __align__(16) unsigned short OH[2][NUM_SEG][LDR]; // 40 KB one-hot B
    __shared__ __align__(16) unsigned short At[2][CHB][LDR];     // 10 KB bf16 A
    __shared__ unsigned char segb[PIX_PER_BLK];                  // 2 KB
    __shared__ int labc[NUM_SEG * WAY];                          // 2 KB
    // total 54 KB -> 2 blocks/CU

    const int bid   = blockIdx.x;        // n*64 + chunk*2 + h
    const int h     = bid & 1;
    const int chunk = (bid >> 1) & 31;
    const int n     = bid >> 6;
    const int t     = threadIdx.x;
    const int lane  = t & 63;
    const int w     = t >> 6;            // wave 0..15
    const int mg    = w & 1;             // ch-local tile base 32*mg
    const int ng    = w >> 1;            // seg group base 32*ng

    const long pixbase = (long)n * HW + chunk * PIX_PER_BLK;

    // zero OH (both buffers incl. pads) + labc
    {
        int4 z; z.x = z.y = z.z = z.w = 0;
        int4* p = (int4*)&OH[0][0][0];
        for (int i = t; i < (2 * NUM_SEG * LDR * 2) / 16; i += NTHREADS) p[i] = z;
        if (h == 0)
            for (int i = t; i < NUM_SEG * WAY; i += NTHREADS) labc[i] = 0;
    }
    __syncthreads();

    // stage seg ids (u8); h==0 blocks also build the label histogram
    for (int p = t; p < PIX_PER_BLK; p += NTHREADS) {
        int s = segs[pixbase + p];
        segb[p] = (unsigned char)s;
        if (h == 0) atomicAdd(&labc[s * 2 + mask[pixbase + p]], 1);
    }

    // A staging: 16 threads/row, float2 each (32 px/chunk, 128 B/row contiguous)
    const int arow = t >> 4;             // 0..63
    const int acol = (t & 15) * 2;       // 0..30
    const float* gA = img + (long)(n * NCH + h * CHB + arow) * HW
                          + chunk * PIX_PER_BLK + acol;

    // load chunk 0
    float2 fc = *(const float2*)(gA);
    __syncthreads();                      // segb + OH zeros visible

    // build chunk 0 into At[0], OH[0]
    *(short2v*)&At[0][arow][acol] = cvt2(fc);
    const bool sc = (t < KW);             // wave-0 lanes 0..31 own one-hot cols
    int s_prev = -1, s_cur = -1;
    if (sc) {
        s_cur = segb[t];
        OH[0][s_cur][t] = 0x3F80;         // bf16 1.0
    }
    fc = *(const float2*)(gA + KW);       // issue load chunk 1
    __syncthreads();                      // At[0], OH[0] visible

    f32x4 acc[2][2] = {};
    const int l15 = lane & 15;
    const int kA  = 8 * (lane >> 4);

    for (int it = 0; it < NITER; ++it) {
        const int cur = it & 1, nxt = cur ^ 1;

        // issue load for chunk it+2 (consumed next iteration)
        float2 fn = fc;
        if (it + 2 < NITER) fn = *(const float2*)(gA + (it + 2) * KW);
        int s_next = 0;
        if (sc && it + 1 < NITER) s_next = segb[(it + 1) * KW + t];

        // MFMA on chunk it (reads cur buffers only)
        short8 a0 = *(const short8*)&At[cur][32 * mg      + l15][kA];
        short8 a1 = *(const short8*)&At[cur][32 * mg + 16 + l15][kA];
        #pragma unroll
        for (int nj = 0; nj < 2; ++nj) {
            short8 b = *(const short8*)&OH[cur][32 * ng + 16 * nj + l15][kA];
            acc[0][nj] = __builtin_amdgcn_mfma_f32_16x16x32_bf16(a0, b, acc[0][nj], 0, 0, 0);
            acc[1][nj] = __builtin_amdgcn_mfma_f32_16x16x32_bf16(a1, b, acc[1][nj], 0, 0, 0);
        }

        // stage chunk it+1 into nxt buffers (disjoint from cur)
        if (it + 1 < NITER) {
            *(short2v*)&At[nxt][arow][acol] = cvt2(fc);   // fc loaded last iter
            if (sc) {
                if (s_prev >= 0 && s_prev != s_next) OH[nxt][s_prev][t] = 0;
                OH[nxt][s_next][t] = 0x3F80;
                s_prev = s_cur;
                s_cur  = s_next;
            }
        }
        __syncthreads();
        fc = fn;
    }

    // epilogue: strip = [8 ng][16 seg][64 ch] fp32 (32 KB, reuse OH), 2 rounds
    float* strip = (float*)&OH[0][0][0];
    float* wsb = ws_part + (long)(n * CHUNKS_PER_IMG + chunk) * PART_ELEMS;
    #pragma unroll
    for (int nj = 0; nj < 2; ++nj) {
        // D layout: col(seg-local)=lane&15, row(ch-local)=4*(lane>>4)+r
        #pragma unroll
        for (int m = 0; m < 2; ++m)
            #pragma unroll
            for (int r = 0; r < 4; ++r)
                strip[ng * (16 * CHB) + l15 * CHB + 32 * mg + 16 * m
                      + 4 * (lane >> 4) + r] = acc[m][nj][r];
        __syncthreads();
        {   // copy: thread t -> strip row t>>3 (=ng*16+sl), 8 floats at (t&7)*8
            const int row = t >> 3;
            const int off = (t & 7) * 8;
            const float4* src = (const float4*)&strip[row * CHB + off];
            float4 v0 = src[0], v1 = src[1];
            float* dst = wsb + (32 * (row >> 4) + 16 * nj + (row & 15)) * NCH
                             + h * CHB + off;
            ((float4*)dst)[0] = v0;
            ((float4*)dst)[1] = v1;
        }
        __syncthreads();
    }

    if (h == 0)
        for (int i = t; i < NUM_SEG * WAY; i += NTHREADS)
            atomicAdd(&labcnt_g[n * NUM_SEG * WAY + i], labc[i]);
}

// sum 32 chunk-partials, divide by count, emit labels
__global__ void reduce_ws_kernel(const float* __restrict__ ws_part,
                                 const int* __restrict__ labcnt,
                                 float* __restrict__ out) {
    const int nmean = TOTAL_SEG * NCH;    // 262144
    int i = blockIdx.x * blockDim.x + threadIdx.x;
    if (i < nmean) {
        int nimg = i >> 15;               // / 32768
        int rem  = i & 32767;             // s*128 + c
        const float* base = ws_part + (long)nimg * 32 * PART_ELEMS + rem;
        float acc = 0.0f;
        #pragma unroll
        for (int j = 0; j < CHUNKS_PER_IMG; ++j)
            acc += base[(long)j * PART_ELEMS];
        int g  = i >> 7;                  // n*256 + s
        int c0 = labcnt[g * 2 + 0];
        int c1 = labcnt[g * 2 + 1];
        out[i] = acc / fmaxf((float)(c0 + c1), 1.0f);
    } else if (i < nmean + TOTAL_SEG) {
        int g = i - nmean;
        out[i] = (labcnt[g * 2 + 1] > labcnt[g * 2 + 0]) ? 1.0f : 0.0f;
    }
}

extern "C" void kernel_launch(void* const* d_in, const int* in_sizes, int n_in,
                              void* d_out, int out_size, void* d_ws, size_t ws_size,
                              hipStream_t stream) {
    const float* img  = (const float*)d_in[0];   // (8,128,256,256) f32
    const int*   mask = (const int*)d_in[1];     // (8,256,256) i32 in [0,2)
    const int*   segs = (const int*)d_in[2];     // (8,256,256) i32 in [0,256)

    float* out = (float*)d_out;

    const size_t part_bytes = (size_t)NPART * PART_ELEMS * sizeof(float); // 32 MB
    float* ws_part = (float*)d_ws;
    int*   labcnt  = (int*)((char*)d_ws + part_bytes);

    hipMemsetAsync(labcnt, 0, (size_t)TOTAL_SEG * WAY * sizeof(int), stream);

    seg_mfma_kernel<<<NBLOCKS, NTHREADS, 0, stream>>>(
        img, mask, segs, ws_part, labcnt);

    const int totalThreads = TOTAL_SEG * NCH + TOTAL_SEG;   // 264192
    reduce_ws_kernel<<<(totalThreads + 255) / 256, 256, 0, stream>>>(
        ws_part, labcnt, out);
}